// Round 9
// baseline (318.714 us; speedup 1.0000x reference)
//
#include <hip/hip_runtime.h>
#include <math.h>

#define DIM 512
#define HEADS 16
#define PD 32
#define NSEQ 2048
#define BATCH 4
#define HIDDEN 2048
#define LOG2E 1.44269504088896f

typedef __attribute__((ext_vector_type(8))) __bf16 bf16x8;
typedef __attribute__((ext_vector_type(4))) float f32x4;
typedef __attribute__((ext_vector_type(16))) float f32x16;

__device__ __forceinline__ ushort f2bf(float f) {
    unsigned u = __float_as_uint(f);
    u = (u + 0x7FFFu + ((u >> 16) & 1u)) >> 16;
    return (ushort)u;
}

__device__ __forceinline__ unsigned cvtpk_bf16(float lo, float hi) {
    unsigned r;
    asm("v_cvt_pk_bf16_f32 %0, %1, %2" : "=v"(r) : "v"(lo), "v"(hi));
    return r;
}

__device__ __forceinline__ float exp2_fast(float x) {
    float r;
    asm("v_exp_f32 %0, %1" : "=v"(r) : "v"(x));
    return r;
}

typedef __attribute__((address_space(1))) const unsigned int g_u32;
typedef __attribute__((address_space(3))) unsigned int l_u32;
__device__ __forceinline__ void gload16(const void* g, void* l) {
    __builtin_amdgcn_global_load_lds((g_u32*)g, (l_u32*)l, 16, 0, 0);
}

__device__ __forceinline__ float gelu_exact(float v) {
    return 0.5f * v * (1.0f + erff(v * 0.70710678118654752f));
}

// All 5 weight transposes in one launch: W[K][N] fp32 -> Wt[N][K] bf16.
__global__ __launch_bounds__(256)
void tr_all_kernel(const float* __restrict__ q_w, const float* __restrict__ kv_w,
                   const float* __restrict__ qkv_w, const float* __restrict__ fc1_w,
                   const float* __restrict__ fc2_w, ushort* __restrict__ wtb)
{
    __shared__ float t[32][33];
    const int bid = blockIdx.x;
    const float* W; ushort* Wt; int K, N, lb;
    if (bid < 256)       { W = q_w;   Wt = wtb;           K = 512;  N = 512;  lb = bid; }
    else if (bid < 768)  { W = kv_w;  Wt = wtb + 262144;  K = 512;  N = 1024; lb = bid - 256; }
    else if (bid < 1536) { W = qkv_w; Wt = wtb + 786432;  K = 512;  N = 1536; lb = bid - 768; }
    else if (bid < 2560) { W = fc1_w; Wt = wtb + 1572864; K = 512;  N = 2048; lb = bid - 1536; }
    else                 { W = fc2_w; Wt = wtb + 2621440; K = 2048; N = 512;  lb = bid - 2560; }
    const int nx = N / 32;
    const int n0 = (lb % nx) * 32, k0 = (lb / nx) * 32;
    const int tid = threadIdx.x;
    const int c = tid & 31, r0 = tid >> 5;
    #pragma unroll
    for (int i = 0; i < 4; ++i) {
        int r = r0 + i * 8;
        t[r][c] = W[(size_t)(k0 + r) * N + n0 + c];
    }
    __syncthreads();
    #pragma unroll
    for (int i = 0; i < 4; ++i) {
        int r = r0 + i * 8;
        Wt[(size_t)(n0 + r) * K + k0 + c] = f2bf(t[c][r]);
    }
}

// bf16 MFMA GEMM: C[M,Nc] = A[M,K] @ Wt[Nc,K]^T + bias
// AIN: 0 = A fp32 (convert in staging), 1 = A bf16.
// EPI: 1 = gelu -> bf16 out; 2 = +res -> fp32 out;
//      3 = bf16 out; cols < qcols scaled by LOG2E; cols >= vcol0 written
//          ONLY transposed to vtp as Vt[b*16+h][pd][ntok] (attention V^T).
template<int AIN, int EPI>
__global__ __launch_bounds__(256)
void mgemm(const void* __restrict__ Ap, const ushort* __restrict__ Bt,
           const float* __restrict__ bias, const float* __restrict__ resp,
           void* __restrict__ Cp, ushort* __restrict__ vtp,
           int M, int K, int Nc, int qcols, int vcol0)
{
    __shared__ __align__(16) ushort As[128 * 32];
    __shared__ __align__(16) ushort Bs[128 * 32];

    const int tid = threadIdx.x;
    const int wid = tid >> 6, ln = tid & 63;
    const int g = ln >> 4, c = ln & 15;
    const int wr = wid >> 1, wc = wid & 1;

    const int nwg = gridDim.x * gridDim.y;
    const int lid = blockIdx.y * gridDim.x + blockIdx.x;
    const int wg  = (lid & 7) * (nwg >> 3) + (lid >> 3);
    const int by = wg / gridDim.x, bx = wg % gridDim.x;
    const int row0 = by * 128, col0 = bx * 128;

    const f32x4 fzero = {0.f, 0.f, 0.f, 0.f};
    f32x4 acc[4][4];
    #pragma unroll
    for (int i = 0; i < 4; ++i)
        #pragma unroll
        for (int j = 0; j < 4; ++j) acc[i][j] = fzero;

    const int srow = tid >> 1, skh = tid & 1;
    const int w3 = (srow >> 1) & 3;
    const int ws0 = (2 * skh) ^ w3, ws1 = (2 * skh + 1) ^ w3;
    ushort* asw0 = &As[srow * 32 + ws0 * 8];
    ushort* asw1 = &As[srow * 32 + ws1 * 8];
    ushort* bsw0 = &Bs[srow * 32 + ws0 * 8];
    ushort* bsw1 = &Bs[srow * 32 + ws1 * 8];

    const int ps = (c >> 1) & 3;

    for (int k0 = 0; k0 < K; k0 += 32) {
        if (AIN == 0) {
            const float4* ap = (const float4*)((const float*)Ap
                                + (size_t)(row0 + srow) * K + k0 + skh * 16);
            float4 f0 = ap[0], f1 = ap[1], f2 = ap[2], f3 = ap[3];
            union { ushort u[16]; uint4 v[2]; } t;
            t.u[0] = f2bf(f0.x);  t.u[1] = f2bf(f0.y);  t.u[2] = f2bf(f0.z);  t.u[3] = f2bf(f0.w);
            t.u[4] = f2bf(f1.x);  t.u[5] = f2bf(f1.y);  t.u[6] = f2bf(f1.z);  t.u[7] = f2bf(f1.w);
            t.u[8] = f2bf(f2.x);  t.u[9] = f2bf(f2.y);  t.u[10] = f2bf(f2.z); t.u[11] = f2bf(f2.w);
            t.u[12] = f2bf(f3.x); t.u[13] = f2bf(f3.y); t.u[14] = f2bf(f3.z); t.u[15] = f2bf(f3.w);
            *(uint4*)asw0 = t.v[0];
            *(uint4*)asw1 = t.v[1];
        } else {
            const uint4* ap = (const uint4*)((const ushort*)Ap
                                + (size_t)(row0 + srow) * K + k0 + skh * 16);
            *(uint4*)asw0 = ap[0];
            *(uint4*)asw1 = ap[1];
        }
        {
            const uint4* bp = (const uint4*)(Bt + (size_t)(col0 + srow) * K + k0 + skh * 16);
            *(uint4*)bsw0 = bp[0];
            *(uint4*)bsw1 = bp[1];
        }
        __syncthreads();

        bf16x8 a[4], b[4];
        #pragma unroll
        for (int mt = 0; mt < 4; ++mt)
            a[mt] = *(const bf16x8*)&As[(wr * 64 + mt * 16 + c) * 32 + ((g ^ ps) * 8)];
        #pragma unroll
        for (int nt = 0; nt < 4; ++nt)
            b[nt] = *(const bf16x8*)&Bs[(wc * 64 + nt * 16 + c) * 32 + ((g ^ ps) * 8)];

        #pragma unroll
        for (int mt = 0; mt < 4; ++mt)
            #pragma unroll
            for (int nt = 0; nt < 4; ++nt)
                acc[mt][nt] = __builtin_amdgcn_mfma_f32_16x16x32_bf16(a[mt], b[nt], acc[mt][nt], 0, 0, 0);
        __syncthreads();
    }

    float bs[4];
    #pragma unroll
    for (int nt = 0; nt < 4; ++nt) bs[nt] = bias[col0 + wc * 64 + nt * 16 + c];

    #pragma unroll
    for (int mt = 0; mt < 4; ++mt) {
        const int rb = row0 + wr * 64 + mt * 16 + g * 4;
        #pragma unroll
        for (int nt = 0; nt < 4; ++nt) {
            const int col = col0 + wc * 64 + nt * 16 + c;
            if (EPI == 3 && col >= vcol0) {
                int cc = col - vcol0;
                int hh = cc >> 5, pd = cc & 31;
                int bq = rb >> 11, ntok = rb & 2047;
                union { ushort u[4]; uint2 v; } pk;
                #pragma unroll
                for (int reg = 0; reg < 4; ++reg)
                    pk.u[reg] = f2bf(acc[mt][nt][reg] + bs[nt]);
                *(uint2*)&vtp[((size_t)(bq * 16 + hh) * 32 + pd) * 2048 + ntok] = pk.v;
            } else {
                #pragma unroll
                for (int reg = 0; reg < 4; ++reg) {
                    int r = rb + reg;
                    float v = acc[mt][nt][reg] + bs[nt];
                    if (EPI == 1) {
                        ((ushort*)Cp)[(size_t)r * Nc + col] = f2bf(gelu_exact(v));
                    } else if (EPI == 2) {
                        ((float*)Cp)[(size_t)r * Nc + col] = v + resp[(size_t)r * Nc + col];
                    } else {
                        float v2 = (col < qcols) ? v * LOG2E : v;
                        ((ushort*)Cp)[(size_t)r * Nc + col] = f2bf(v2);
                    }
                }
            }
        }
    }
}

// MFMA flash attention + fused residual + LayerNorm epilogue.
// Maxless exp2-domain softmax. l computed ON THE MFMA PIPE: alongside each
// PV MFMA, lacc = mfma(ones, P^T, lacc) gives D[i][q] = sum_k P^T[k][q] in
// every reg — l = lacc[0] per lane, zero shuffles, no serial VALU add chain.
// KVBLK=128 double-buffered via global_load_lds (pre-swizzled source, linear
// LDS dest), one barrier per tile. V^T precomputed by projection GEMM.
// S^T = mfma(K, Q·log2e); P repack via cvt_pk + permlane32_swap;
// O^T = mfma(V^T, P^T). setprio(1) wraps the MFMA clusters (T5).
// Epilogue: x = res + O/l (buggy heads-merge perm preserved), then row
// LayerNorm in-register (32-lane half-wave owns one full 512-col row).
__global__ __launch_bounds__(256)
void attn_mfma_kernel(const ushort* __restrict__ qb_, int qstride, int qoff,
                      const ushort* __restrict__ kb_, int kstride, int koff,
                      const ushort* __restrict__ vtg,
                      const float* res, const float* __restrict__ gptr,
                      const float* __restrict__ bptr,
                      float* nf32, ushort* __restrict__ nb16)
{
    __shared__ __align__(16) ushort Klds[2][128 * 32];
    __shared__ __align__(16) ushort Vtlds[2][32 * 128];

    const int tid = threadIdx.x;
    const int w   = tid >> 6;
    const int ln  = tid & 63;
    const int c32 = ln & 31;
    const int hi  = ln >> 5;

    const int bid = blockIdx.x;
    const int xcd = bid & 7, jj = bid >> 3;
    const int bh = xcd + 8 * (jj >> 4);
    const int qt = jj & 15;
    const int b = bh >> 4, h = bh & 15;
    const size_t rowbase = (size_t)b * NSEQ;
    const int qt0 = qt * 128 + w * 32;
    const int n = qt0 + c32;

    bf16x8 qfrag[2];
    #pragma unroll
    for (int ph = 0; ph < 2; ++ph)
        qfrag[ph] = *(const bf16x8*)(qb_ + (rowbase + n) * qstride + qoff
                                     + h * PD + ph * 16 + hi * 8);

    // all-ones bf16 A-operand for the l-MFMA
    union { ushort u[8]; bf16x8 v; } ones;
    #pragma unroll
    for (int j = 0; j < 8; ++j) ones.u[j] = 0x3F80;

    const ushort* ks[2];
    const ushort* vs[2];
    int kd[2], vd[2];
    #pragma unroll
    for (int i = 0; i < 2; ++i) {
        int ch = 2 * w + i;
        int kvc = ch * 16 + (ln >> 2);
        int q4  = (ln & 3) ^ ((kvc >> 1) & 3);
        ks[i] = kb_ + (rowbase + kvc) * kstride + koff + h * PD + q4 * 8;
        kd[i] = ch * 512;
        int pdc = ch * 4 + (ln >> 4);
        int kv0 = ((ln & 15) ^ (pdc & 15)) * 8;
        vs[i] = vtg + ((size_t)bh * PD + pdc) * 2048 + kv0;
        vd[i] = ch * 512;
    }

#define STAGE(bi, trow)                                              \
    {                                                                \
        gload16(ks[0] + (size_t)(trow) * kstride, &Klds[bi][kd[0]]); \
        gload16(ks[1] + (size_t)(trow) * kstride, &Klds[bi][kd[1]]); \
        gload16(vs[0] + (trow), &Vtlds[bi][vd[0]]);                  \
        gload16(vs[1] + (trow), &Vtlds[bi][vd[1]]);                  \
    }

    f32x16 oacc, lacc, zero16;
    #pragma unroll
    for (int i = 0; i < 16; ++i) { oacc[i] = 0.f; lacc[i] = 0.f; zero16[i] = 0.f; }

    STAGE(0, 0);

    for (int t = 0; t < NSEQ / 128; ++t) {
        __syncthreads();
        if (t < NSEQ / 128 - 1) STAGE((t + 1) & 1, (t + 1) * 128);
        const ushort* Kb = Klds[t & 1];
        const ushort* Vb = Vtlds[t & 1];

        #pragma unroll
        for (int hh = 0; hh < 2; ++hh) {
            bf16x8 kf[2][2];
            #pragma unroll
            for (int kt = 0; kt < 2; ++kt)
                #pragma unroll
                for (int ph = 0; ph < 2; ++ph) {
                    int slot = (2 * ph + hi) ^ ((c32 >> 1) & 3);
                    kf[kt][ph] = *(const bf16x8*)&Kb[(hh * 64 + kt * 32 + c32) * 32 + slot * 8];
                }
            bf16x8 vf[4];
            #pragma unroll
            for (int j = 0; j < 4; ++j) {
                int slot = (hh * 8 + 2 * j + hi) ^ (c32 & 15);
                vf[j] = *(const bf16x8*)&Vb[c32 * 128 + slot * 8];
            }

            f32x16 st[2];
            __builtin_amdgcn_s_setprio(1);
            #pragma unroll
            for (int kt = 0; kt < 2; ++kt) {
                st[kt] = __builtin_amdgcn_mfma_f32_32x32x16_bf16(kf[kt][0], qfrag[0], zero16, 0, 0, 0);
                st[kt] = __builtin_amdgcn_mfma_f32_32x32x16_bf16(kf[kt][1], qfrag[1], st[kt], 0, 0, 0);
            }
            __builtin_amdgcn_s_setprio(0);

            // maxless exp2-domain P
            #pragma unroll
            for (int kt = 0; kt < 2; ++kt)
                #pragma unroll
                for (int i = 0; i < 16; ++i)
                    st[kt][i] = exp2_fast(st[kt][i]);

            unsigned wpk[2][4][2];
            #pragma unroll
            for (int kt = 0; kt < 2; ++kt)
                #pragma unroll
                for (int rg = 0; rg < 4; ++rg) {
                    wpk[kt][rg][0] = cvtpk_bf16(st[kt][rg * 4 + 0], st[kt][rg * 4 + 1]);
                    wpk[kt][rg][1] = cvtpk_bf16(st[kt][rg * 4 + 2], st[kt][rg * 4 + 3]);
                }

            __builtin_amdgcn_s_setprio(1);
            #pragma unroll
            for (int j = 0; j < 4; ++j) {
                int kt = j >> 1, rg0 = 2 * (j & 1);
                unsigned x0 = wpk[kt][rg0][0], y0 = wpk[kt][rg0 + 1][0];
                unsigned x1 = wpk[kt][rg0][1], y1 = wpk[kt][rg0 + 1][1];
                asm("v_permlane32_swap_b32 %0, %1" : "+v"(x0), "+v"(y0));
                asm("v_permlane32_swap_b32 %0, %1" : "+v"(x1), "+v"(y1));
                union { unsigned u[4]; bf16x8 v; } pf;
                pf.u[0] = x0; pf.u[1] = x1; pf.u[2] = y0; pf.u[3] = y1;
                oacc = __builtin_amdgcn_mfma_f32_32x32x16_bf16(vf[j], pf.v, oacc, 0, 0, 0);
                lacc = __builtin_amdgcn_mfma_f32_32x32x16_bf16(ones.v, pf.v, lacc, 0, 0, 0);
            }
            __builtin_amdgcn_s_setprio(0);
        }
    }
#undef STAGE

    // ---- fused epilogue: x = res + O/l (heads-merge perm), then LayerNorm
    const float inv = 1.0f / lacc[0];
    const int row2 = h * 128 + (n >> 4);
    const int colb = (n & 15) * PD;
    const size_t rowoff = (rowbase + row2) * DIM;

    float xv[16];
    float s = 0.f, ss = 0.f;
    #pragma unroll
    for (int ch = 0; ch < 4; ++ch) {
        float4 r4 = *(const float4*)&res[rowoff + colb + ch * 8 + hi * 4];
        #pragma unroll
        for (int q = 0; q < 4; ++q) {
            float rv = (q == 0) ? r4.x : (q == 1) ? r4.y : (q == 2) ? r4.z : r4.w;
            float x = rv + oacc[ch * 4 + q] * inv;
            xv[ch * 4 + q] = x; s += x; ss += x * x;
        }
    }
    s += __shfl_xor(s, 1);  ss += __shfl_xor(ss, 1);
    s += __shfl_xor(s, 2);  ss += __shfl_xor(ss, 2);
    s += __shfl_xor(s, 4);  ss += __shfl_xor(ss, 4);
    s += __shfl_xor(s, 8);  ss += __shfl_xor(ss, 8);
    s += __shfl_xor(s, 32); ss += __shfl_xor(ss, 32);
    float mu = s * (1.0f / DIM);
    float var = ss * (1.0f / DIM) - mu * mu;
    float rr = rsqrtf(var + 1e-5f);

    #pragma unroll
    for (int ch = 0; ch < 4; ++ch) {
        const int off = colb + ch * 8 + hi * 4;
        float4 g4 = *(const float4*)&gptr[off];
        float4 b4 = *(const float4*)&bptr[off];
        float y0 = (xv[ch * 4 + 0] - mu) * rr * g4.x + b4.x;
        float y1 = (xv[ch * 4 + 1] - mu) * rr * g4.y + b4.y;
        float y2 = (xv[ch * 4 + 2] - mu) * rr * g4.z + b4.z;
        float y3 = (xv[ch * 4 + 3] - mu) * rr * g4.w + b4.w;
        float4 yv = {y0, y1, y2, y3};
        *(float4*)&nf32[rowoff + off] = yv;
        uint2 pk = {cvtpk_bf16(y0, y1), cvtpk_bf16(y2, y3)};
        *(uint2*)&nb16[rowoff + off] = pk;
    }
}

extern "C" void kernel_launch(void* const* d_in, const int* in_sizes, int n_in,
                              void* d_out, int out_size, void* d_ws, size_t ws_size,
                              hipStream_t stream)
{
    const float* x1     = (const float*)d_in[0];
    const float* x2     = (const float*)d_in[1];
    const float* qkv_w  = (const float*)d_in[2];
    const float* qkv_b  = (const float*)d_in[3];
    const float* q_w    = (const float*)d_in[4];
    const float* q_b    = (const float*)d_in[5];
    const float* kv_w   = (const float*)d_in[6];
    const float* kv_b   = (const float*)d_in[7];
    const float* norm_g = (const float*)d_in[8];
    const float* norm_b = (const float*)d_in[9];
    const float* fc1_w  = (const float*)d_in[10];
    const float* fc1_b  = (const float*)d_in[11];
    const float* fc2_w  = (const float*)d_in[12];
    const float* fc2_b  = (const float*)d_in[13];
    float* out = (float*)d_out;
    float* ws  = (float*)d_ws;

    const int M = BATCH * NSEQ;  // 8192
    const int BIG = 1 << 30;

    // ws layout (float offsets), all regions disjoint:
    // [0,2M) weights | [2M,10M) proj_u | [10.5M,12.5M) VtG
    // [13M,17M) n1f32 | [17M,19M) n1b16 | [19M,21M) n2b16
    ushort* wtb    = (ushort*)ws;
    ushort* q_wt   = wtb;
    ushort* kv_wt  = wtb + 262144;
    ushort* qkv_wt = wtb + 786432;
    ushort* fc1_wt = wtb + 1572864;
    ushort* fc2_wt = wtb + 2621440;
    ushort* proj_u = (ushort*)(ws + (size_t)2 * 1024 * 1024);
    ushort* kvb16  = proj_u;                            // 8192x1024
    ushort* qb16   = proj_u + (size_t)8192 * 1024;      // 8192x512
    ushort* qkvb16 = proj_u;                            // 8192x1536
    ushort* hbuf   = proj_u;                            // 8192x2048
    ushort* VtG    = (ushort*)(ws + (size_t)21 * 512 * 1024);  // 10.5M floats
    float*  n1f32  = ws + (size_t)13 * 1024 * 1024;
    ushort* n1b16  = (ushort*)(ws + (size_t)17 * 1024 * 1024);
    ushort* n2b16  = (ushort*)(ws + (size_t)19 * 1024 * 1024);

    dim3 blk(256);

    tr_all_kernel<<<dim3(3584), blk, 0, stream>>>(q_w, kv_w, qkv_w, fc1_w, fc2_w, wtb);

    // ---- cross attention ----
    mgemm<0, 3><<<dim3(1024 / 128, M / 128), blk, 0, stream>>>(
        x1, kv_wt, kv_b, nullptr, kvb16, VtG, M, DIM, 1024, 0, 512);
    mgemm<0, 3><<<dim3(512 / 128, M / 128), blk, 0, stream>>>(
        x2, q_wt, q_b, nullptr, qb16, nullptr, M, DIM, 512, 512, BIG);
    attn_mfma_kernel<<<dim3(1024), blk, 0, stream>>>(
        qb16, 512, 0, kvb16, 1024, 0, VtG, x2, norm_g, norm_b, n1f32, n1b16);

    // ---- self attention ----
    mgemm<1, 3><<<dim3(1536 / 128, M / 128), blk, 0, stream>>>(
        n1b16, qkv_wt, qkv_b, nullptr, qkvb16, VtG, M, DIM, 1536, 512, 1024);
    attn_mfma_kernel<<<dim3(1024), blk, 0, stream>>>(
        qkvb16, 1536, 0, qkvb16, 1536, 512, VtG, n1f32, norm_g, norm_b, n1f32, n2b16);

    // ---- MLP ----
    mgemm<1, 1><<<dim3(HIDDEN / 128, M / 128), blk, 0, stream>>>(
        n2b16, fc1_wt, fc1_b, nullptr, hbuf, nullptr, M, DIM, HIDDEN, 0, BIG);
    mgemm<1, 2><<<dim3(512 / 128, M / 128), blk, 0, stream>>>(
        hbuf, fc2_wt, fc2_b, n1f32, out, nullptr, M, HIDDEN, DIM, 0, BIG);
}

// Round 10
// 305.662 us; speedup vs baseline: 1.0427x; 1.0427x over previous
//
#include <hip/hip_runtime.h>
#include <math.h>

#define DIM 512
#define HEADS 16
#define PD 32
#define NSEQ 2048
#define BATCH 4
#define HIDDEN 2048
#define LOG2E 1.44269504088896f

typedef __attribute__((ext_vector_type(8))) __bf16 bf16x8;
typedef __attribute__((ext_vector_type(4))) float f32x4;
typedef __attribute__((ext_vector_type(16))) float f32x16;

__device__ __forceinline__ ushort f2bf(float f) {
    unsigned u = __float_as_uint(f);
    u = (u + 0x7FFFu + ((u >> 16) & 1u)) >> 16;
    return (ushort)u;
}

__device__ __forceinline__ unsigned cvtpk_bf16(float lo, float hi) {
    unsigned r;
    asm("v_cvt_pk_bf16_f32 %0, %1, %2" : "=v"(r) : "v"(lo), "v"(hi));
    return r;
}

__device__ __forceinline__ float exp2_fast(float x) {
    float r;
    asm("v_exp_f32 %0, %1" : "=v"(r) : "v"(x));
    return r;
}

typedef __attribute__((address_space(1))) const unsigned int g_u32;
typedef __attribute__((address_space(3))) unsigned int l_u32;
__device__ __forceinline__ void gload16(const void* g, void* l) {
    __builtin_amdgcn_global_load_lds((g_u32*)g, (l_u32*)l, 16, 0, 0);
}

__device__ __forceinline__ float gelu_exact(float v) {
    return 0.5f * v * (1.0f + erff(v * 0.70710678118654752f));
}

// All 5 weight transposes in one launch: W[K][N] fp32 -> Wt[N][K] bf16.
__global__ __launch_bounds__(256)
void tr_all_kernel(const float* __restrict__ q_w, const float* __restrict__ kv_w,
                   const float* __restrict__ qkv_w, const float* __restrict__ fc1_w,
                   const float* __restrict__ fc2_w, ushort* __restrict__ wtb)
{
    __shared__ float t[32][33];
    const int bid = blockIdx.x;
    const float* W; ushort* Wt; int K, N, lb;
    if (bid < 256)       { W = q_w;   Wt = wtb;           K = 512;  N = 512;  lb = bid; }
    else if (bid < 768)  { W = kv_w;  Wt = wtb + 262144;  K = 512;  N = 1024; lb = bid - 256; }
    else if (bid < 1536) { W = qkv_w; Wt = wtb + 786432;  K = 512;  N = 1536; lb = bid - 768; }
    else if (bid < 2560) { W = fc1_w; Wt = wtb + 1572864; K = 512;  N = 2048; lb = bid - 1536; }
    else                 { W = fc2_w; Wt = wtb + 2621440; K = 2048; N = 512;  lb = bid - 2560; }
    const int nx = N / 32;
    const int n0 = (lb % nx) * 32, k0 = (lb / nx) * 32;
    const int tid = threadIdx.x;
    const int c = tid & 31, r0 = tid >> 5;
    #pragma unroll
    for (int i = 0; i < 4; ++i) {
        int r = r0 + i * 8;
        t[r][c] = W[(size_t)(k0 + r) * N + n0 + c];
    }
    __syncthreads();
    #pragma unroll
    for (int i = 0; i < 4; ++i) {
        int r = r0 + i * 8;
        Wt[(size_t)(n0 + r) * K + k0 + c] = f2bf(t[c][r]);
    }
}

// bf16 MFMA GEMM: C[M,Nc] = A[M,K] @ Wt[Nc,K]^T + bias
// AIN: 0 = A fp32 (convert in staging), 1 = A bf16.
// EPI: 1 = gelu -> bf16 out; 2 = +res -> fp32 out;
//      3 = bf16 out; cols < qcols scaled by LOG2E; cols >= vcol0 written
//          ONLY transposed to vtp as Vt[b*16+h][pd][ntok] (attention V^T).
template<int AIN, int EPI>
__global__ __launch_bounds__(256)
void mgemm(const void* __restrict__ Ap, const ushort* __restrict__ Bt,
           const float* __restrict__ bias, const float* __restrict__ resp,
           void* __restrict__ Cp, ushort* __restrict__ vtp,
           int M, int K, int Nc, int qcols, int vcol0)
{
    __shared__ __align__(16) ushort As[128 * 32];
    __shared__ __align__(16) ushort Bs[128 * 32];

    const int tid = threadIdx.x;
    const int wid = tid >> 6, ln = tid & 63;
    const int g = ln >> 4, c = ln & 15;
    const int wr = wid >> 1, wc = wid & 1;

    const int nwg = gridDim.x * gridDim.y;
    const int lid = blockIdx.y * gridDim.x + blockIdx.x;
    const int wg  = (lid & 7) * (nwg >> 3) + (lid >> 3);
    const int by = wg / gridDim.x, bx = wg % gridDim.x;
    const int row0 = by * 128, col0 = bx * 128;

    const f32x4 fzero = {0.f, 0.f, 0.f, 0.f};
    f32x4 acc[4][4];
    #pragma unroll
    for (int i = 0; i < 4; ++i)
        #pragma unroll
        for (int j = 0; j < 4; ++j) acc[i][j] = fzero;

    const int srow = tid >> 1, skh = tid & 1;
    const int w3 = (srow >> 1) & 3;
    const int ws0 = (2 * skh) ^ w3, ws1 = (2 * skh + 1) ^ w3;
    ushort* asw0 = &As[srow * 32 + ws0 * 8];
    ushort* asw1 = &As[srow * 32 + ws1 * 8];
    ushort* bsw0 = &Bs[srow * 32 + ws0 * 8];
    ushort* bsw1 = &Bs[srow * 32 + ws1 * 8];

    const int ps = (c >> 1) & 3;

    for (int k0 = 0; k0 < K; k0 += 32) {
        if (AIN == 0) {
            const float4* ap = (const float4*)((const float*)Ap
                                + (size_t)(row0 + srow) * K + k0 + skh * 16);
            float4 f0 = ap[0], f1 = ap[1], f2 = ap[2], f3 = ap[3];
            union { ushort u[16]; uint4 v[2]; } t;
            t.u[0] = f2bf(f0.x);  t.u[1] = f2bf(f0.y);  t.u[2] = f2bf(f0.z);  t.u[3] = f2bf(f0.w);
            t.u[4] = f2bf(f1.x);  t.u[5] = f2bf(f1.y);  t.u[6] = f2bf(f1.z);  t.u[7] = f2bf(f1.w);
            t.u[8] = f2bf(f2.x);  t.u[9] = f2bf(f2.y);  t.u[10] = f2bf(f2.z); t.u[11] = f2bf(f2.w);
            t.u[12] = f2bf(f3.x); t.u[13] = f2bf(f3.y); t.u[14] = f2bf(f3.z); t.u[15] = f2bf(f3.w);
            *(uint4*)asw0 = t.v[0];
            *(uint4*)asw1 = t.v[1];
        } else {
            const uint4* ap = (const uint4*)((const ushort*)Ap
                                + (size_t)(row0 + srow) * K + k0 + skh * 16);
            *(uint4*)asw0 = ap[0];
            *(uint4*)asw1 = ap[1];
        }
        {
            const uint4* bp = (const uint4*)(Bt + (size_t)(col0 + srow) * K + k0 + skh * 16);
            *(uint4*)bsw0 = bp[0];
            *(uint4*)bsw1 = bp[1];
        }
        __syncthreads();

        bf16x8 a[4], b[4];
        #pragma unroll
        for (int mt = 0; mt < 4; ++mt)
            a[mt] = *(const bf16x8*)&As[(wr * 64 + mt * 16 + c) * 32 + ((g ^ ps) * 8)];
        #pragma unroll
        for (int nt = 0; nt < 4; ++nt)
            b[nt] = *(const bf16x8*)&Bs[(wc * 64 + nt * 16 + c) * 32 + ((g ^ ps) * 8)];

        #pragma unroll
        for (int mt = 0; mt < 4; ++mt)
            #pragma unroll
            for (int nt = 0; nt < 4; ++nt)
                acc[mt][nt] = __builtin_amdgcn_mfma_f32_16x16x32_bf16(a[mt], b[nt], acc[mt][nt], 0, 0, 0);
        __syncthreads();
    }

    float bs[4];
    #pragma unroll
    for (int nt = 0; nt < 4; ++nt) bs[nt] = bias[col0 + wc * 64 + nt * 16 + c];

    #pragma unroll
    for (int mt = 0; mt < 4; ++mt) {
        const int rb = row0 + wr * 64 + mt * 16 + g * 4;
        #pragma unroll
        for (int nt = 0; nt < 4; ++nt) {
            const int col = col0 + wc * 64 + nt * 16 + c;
            if (EPI == 3 && col >= vcol0) {
                int cc = col - vcol0;
                int hh = cc >> 5, pd = cc & 31;
                int bq = rb >> 11, ntok = rb & 2047;
                union { ushort u[4]; uint2 v; } pk;
                #pragma unroll
                for (int reg = 0; reg < 4; ++reg)
                    pk.u[reg] = f2bf(acc[mt][nt][reg] + bs[nt]);
                *(uint2*)&vtp[((size_t)(bq * 16 + hh) * 32 + pd) * 2048 + ntok] = pk.v;
            } else {
                #pragma unroll
                for (int reg = 0; reg < 4; ++reg) {
                    int r = rb + reg;
                    float v = acc[mt][nt][reg] + bs[nt];
                    if (EPI == 1) {
                        ((ushort*)Cp)[(size_t)r * Nc + col] = f2bf(gelu_exact(v));
                    } else if (EPI == 2) {
                        ((float*)Cp)[(size_t)r * Nc + col] = v + resp[(size_t)r * Nc + col];
                    } else {
                        float v2 = (col < qcols) ? v * LOG2E : v;
                        ((ushort*)Cp)[(size_t)r * Nc + col] = f2bf(v2);
                    }
                }
            }
        }
    }
}

// MFMA flash attention + fused residual + LayerNorm epilogue.
// Maxless exp2-domain softmax; l on VALU with FOUR independent partial-sum
// chains (depth 8 each, interleaves with exp2 issue) + 1 shfl per hh.
// KVBLK=128 double-buffered via global_load_lds (pre-swizzled source, linear
// LDS dest), one barrier per tile. V^T precomputed by projection GEMM.
// S^T = mfma(K, Q·log2e); P repack via cvt_pk + permlane32_swap;
// O^T = mfma(V^T, P^T). setprio(1) wraps MFMA clusters (T5, m191).
// Epilogue: x = res + O/l (buggy heads-merge perm preserved), then row
// LayerNorm in-register (32-lane half-wave owns one full 512-col row).
__global__ __launch_bounds__(256)
void attn_mfma_kernel(const ushort* __restrict__ qb_, int qstride, int qoff,
                      const ushort* __restrict__ kb_, int kstride, int koff,
                      const ushort* __restrict__ vtg,
                      const float* res, const float* __restrict__ gptr,
                      const float* __restrict__ bptr,
                      float* nf32, ushort* __restrict__ nb16)
{
    __shared__ __align__(16) ushort Klds[2][128 * 32];
    __shared__ __align__(16) ushort Vtlds[2][32 * 128];

    const int tid = threadIdx.x;
    const int w   = tid >> 6;
    const int ln  = tid & 63;
    const int c32 = ln & 31;
    const int hi  = ln >> 5;

    const int bid = blockIdx.x;
    const int xcd = bid & 7, jj = bid >> 3;
    const int bh = xcd + 8 * (jj >> 4);
    const int qt = jj & 15;
    const int b = bh >> 4, h = bh & 15;
    const size_t rowbase = (size_t)b * NSEQ;
    const int qt0 = qt * 128 + w * 32;
    const int n = qt0 + c32;

    bf16x8 qfrag[2];
    #pragma unroll
    for (int ph = 0; ph < 2; ++ph)
        qfrag[ph] = *(const bf16x8*)(qb_ + (rowbase + n) * qstride + qoff
                                     + h * PD + ph * 16 + hi * 8);

    const ushort* ks[2];
    const ushort* vs[2];
    int kd[2], vd[2];
    #pragma unroll
    for (int i = 0; i < 2; ++i) {
        int ch = 2 * w + i;
        int kvc = ch * 16 + (ln >> 2);
        int q4  = (ln & 3) ^ ((kvc >> 1) & 3);
        ks[i] = kb_ + (rowbase + kvc) * kstride + koff + h * PD + q4 * 8;
        kd[i] = ch * 512;
        int pdc = ch * 4 + (ln >> 4);
        int kv0 = ((ln & 15) ^ (pdc & 15)) * 8;
        vs[i] = vtg + ((size_t)bh * PD + pdc) * 2048 + kv0;
        vd[i] = ch * 512;
    }

#define STAGE(bi, trow)                                              \
    {                                                                \
        gload16(ks[0] + (size_t)(trow) * kstride, &Klds[bi][kd[0]]); \
        gload16(ks[1] + (size_t)(trow) * kstride, &Klds[bi][kd[1]]); \
        gload16(vs[0] + (trow), &Vtlds[bi][vd[0]]);                  \
        gload16(vs[1] + (trow), &Vtlds[bi][vd[1]]);                  \
    }

    f32x16 oacc, zero16;
    #pragma unroll
    for (int i = 0; i < 16; ++i) { oacc[i] = 0.f; zero16[i] = 0.f; }
    float l = 0.f;

    STAGE(0, 0);

    for (int t = 0; t < NSEQ / 128; ++t) {
        __syncthreads();
        if (t < NSEQ / 128 - 1) STAGE((t + 1) & 1, (t + 1) * 128);
        const ushort* Kb = Klds[t & 1];
        const ushort* Vb = Vtlds[t & 1];

        #pragma unroll
        for (int hh = 0; hh < 2; ++hh) {
            bf16x8 kf[2][2];
            #pragma unroll
            for (int kt = 0; kt < 2; ++kt)
                #pragma unroll
                for (int ph = 0; ph < 2; ++ph) {
                    int slot = (2 * ph + hi) ^ ((c32 >> 1) & 3);
                    kf[kt][ph] = *(const bf16x8*)&Kb[(hh * 64 + kt * 32 + c32) * 32 + slot * 8];
                }
            bf16x8 vf[4];
            #pragma unroll
            for (int j = 0; j < 4; ++j) {
                int slot = (hh * 8 + 2 * j + hi) ^ (c32 & 15);
                vf[j] = *(const bf16x8*)&Vb[c32 * 128 + slot * 8];
            }

            f32x16 st[2];
            __builtin_amdgcn_s_setprio(1);
            #pragma unroll
            for (int kt = 0; kt < 2; ++kt) {
                st[kt] = __builtin_amdgcn_mfma_f32_32x32x16_bf16(kf[kt][0], qfrag[0], zero16, 0, 0, 0);
                st[kt] = __builtin_amdgcn_mfma_f32_32x32x16_bf16(kf[kt][1], qfrag[1], st[kt], 0, 0, 0);
            }
            __builtin_amdgcn_s_setprio(0);

            // maxless exp2-domain P; rsum via 4 independent chains (depth 8)
            float r0 = 0.f, r1 = 0.f, r2 = 0.f, r3 = 0.f;
            #pragma unroll
            for (int kt = 0; kt < 2; ++kt) {
                #pragma unroll
                for (int i = 0; i < 4; ++i) {
                    float p0 = exp2_fast(st[kt][i * 4 + 0]);
                    float p1 = exp2_fast(st[kt][i * 4 + 1]);
                    float p2 = exp2_fast(st[kt][i * 4 + 2]);
                    float p3 = exp2_fast(st[kt][i * 4 + 3]);
                    st[kt][i * 4 + 0] = p0; r0 += p0;
                    st[kt][i * 4 + 1] = p1; r1 += p1;
                    st[kt][i * 4 + 2] = p2; r2 += p2;
                    st[kt][i * 4 + 3] = p3; r3 += p3;
                }
            }
            float rsum = (r0 + r1) + (r2 + r3);
            rsum += __shfl_xor(rsum, 32);
            l += rsum;

            unsigned wpk[2][4][2];
            #pragma unroll
            for (int kt = 0; kt < 2; ++kt)
                #pragma unroll
                for (int rg = 0; rg < 4; ++rg) {
                    wpk[kt][rg][0] = cvtpk_bf16(st[kt][rg * 4 + 0], st[kt][rg * 4 + 1]);
                    wpk[kt][rg][1] = cvtpk_bf16(st[kt][rg * 4 + 2], st[kt][rg * 4 + 3]);
                }

            __builtin_amdgcn_s_setprio(1);
            #pragma unroll
            for (int j = 0; j < 4; ++j) {
                int kt = j >> 1, rg0 = 2 * (j & 1);
                unsigned x0 = wpk[kt][rg0][0], y0 = wpk[kt][rg0 + 1][0];
                unsigned x1 = wpk[kt][rg0][1], y1 = wpk[kt][rg0 + 1][1];
                asm("v_permlane32_swap_b32 %0, %1" : "+v"(x0), "+v"(y0));
                asm("v_permlane32_swap_b32 %0, %1" : "+v"(x1), "+v"(y1));
                union { unsigned u[4]; bf16x8 v; } pf;
                pf.u[0] = x0; pf.u[1] = x1; pf.u[2] = y0; pf.u[3] = y1;
                oacc = __builtin_amdgcn_mfma_f32_32x32x16_bf16(vf[j], pf.v, oacc, 0, 0, 0);
            }
            __builtin_amdgcn_s_setprio(0);
        }
    }
#undef STAGE

    // ---- fused epilogue: x = res + O/l (heads-merge perm), then LayerNorm
    const float inv = 1.0f / l;
    const int row2 = h * 128 + (n >> 4);
    const int colb = (n & 15) * PD;
    const size_t rowoff = (rowbase + row2) * DIM;

    float xv[16];
    float s = 0.f, ss = 0.f;
    #pragma unroll
    for (int ch = 0; ch < 4; ++ch) {
        float4 r4 = *(const float4*)&res[rowoff + colb + ch * 8 + hi * 4];
        #pragma unroll
        for (int q = 0; q < 4; ++q) {
            float rv = (q == 0) ? r4.x : (q == 1) ? r4.y : (q == 2) ? r4.z : r4.w;
            float x = rv + oacc[ch * 4 + q] * inv;
            xv[ch * 4 + q] = x; s += x; ss += x * x;
        }
    }
    s += __shfl_xor(s, 1);  ss += __shfl_xor(ss, 1);
    s += __shfl_xor(s, 2);  ss += __shfl_xor(ss, 2);
    s += __shfl_xor(s, 4);  ss += __shfl_xor(ss, 4);
    s += __shfl_xor(s, 8);  ss += __shfl_xor(ss, 8);
    s += __shfl_xor(s, 32); ss += __shfl_xor(ss, 32);
    float mu = s * (1.0f / DIM);
    float var = ss * (1.0f / DIM) - mu * mu;
    float rr = rsqrtf(var + 1e-5f);

    #pragma unroll
    for (int ch = 0; ch < 4; ++ch) {
        const int off = colb + ch * 8 + hi * 4;
        float4 g4 = *(const float4*)&gptr[off];
        float4 b4 = *(const float4*)&bptr[off];
        float y0 = (xv[ch * 4 + 0] - mu) * rr * g4.x + b4.x;
        float y1 = (xv[ch * 4 + 1] - mu) * rr * g4.y + b4.y;
        float y2 = (xv[ch * 4 + 2] - mu) * rr * g4.z + b4.z;
        float y3 = (xv[ch * 4 + 3] - mu) * rr * g4.w + b4.w;
        float4 yv = {y0, y1, y2, y3};
        *(float4*)&nf32[rowoff + off] = yv;
        uint2 pk = {cvtpk_bf16(y0, y1), cvtpk_bf16(y2, y3)};
        *(uint2*)&nb16[rowoff + off] = pk;
    }
}

extern "C" void kernel_launch(void* const* d_in, const int* in_sizes, int n_in,
                              void* d_out, int out_size, void* d_ws, size_t ws_size,
                              hipStream_t stream)
{
    const float* x1     = (const float*)d_in[0];
    const float* x2     = (const float*)d_in[1];
    const float* qkv_w  = (const float*)d_in[2];
    const float* qkv_b  = (const float*)d_in[3];
    const float* q_w    = (const float*)d_in[4];
    const float* q_b    = (const float*)d_in[5];
    const float* kv_w   = (const float*)d_in[6];
    const float* kv_b   = (const float*)d_in[7];
    const float* norm_g = (const float*)d_in[8];
    const float* norm_b = (const float*)d_in[9];
    const float* fc1_w  = (const float*)d_in[10];
    const float* fc1_b  = (const float*)d_in[11];
    const float* fc2_w  = (const float*)d_in[12];
    const float* fc2_b  = (const float*)d_in[13];
    float* out = (float*)d_out;
    float* ws  = (float*)d_ws;

    const int M = BATCH * NSEQ;  // 8192
    const int BIG = 1 << 30;

    // ws layout (float offsets), all regions disjoint:
    // [0,2M) weights | [2M,10M) proj_u | [10.5M,12.5M) VtG
    // [13M,17M) n1f32 | [17M,19M) n1b16 | [19M,21M) n2b16
    ushort* wtb    = (ushort*)ws;
    ushort* q_wt   = wtb;
    ushort* kv_wt  = wtb + 262144;
    ushort* qkv_wt = wtb + 786432;
    ushort* fc1_wt = wtb + 1572864;
    ushort* fc2_wt = wtb + 2621440;
    ushort* proj_u = (ushort*)(ws + (size_t)2 * 1024 * 1024);
    ushort* kvb16  = proj_u;                            // 8192x1024
    ushort* qb16   = proj_u + (size_t)8192 * 1024;      // 8192x512
    ushort* qkvb16 = proj_u;                            // 8192x1536
    ushort* hbuf   = proj_u;                            // 8192x2048
    ushort* VtG    = (ushort*)(ws + (size_t)21 * 512 * 1024);  // 10.5M floats
    float*  n1f32  = ws + (size_t)13 * 1024 * 1024;
    ushort* n1b16  = (ushort*)(ws + (size_t)17 * 1024 * 1024);
    ushort* n2b16  = (ushort*)(ws + (size_t)19 * 1024 * 1024);

    dim3 blk(256);

    tr_all_kernel<<<dim3(3584), blk, 0, stream>>>(q_w, kv_w, qkv_w, fc1_w, fc2_w, wtb);

    // ---- cross attention ----
    mgemm<0, 3><<<dim3(1024 / 128, M / 128), blk, 0, stream>>>(
        x1, kv_wt, kv_b, nullptr, kvb16, VtG, M, DIM, 1024, 0, 512);
    mgemm<0, 3><<<dim3(512 / 128, M / 128), blk, 0, stream>>>(
        x2, q_wt, q_b, nullptr, qb16, nullptr, M, DIM, 512, 512, BIG);
    attn_mfma_kernel<<<dim3(1024), blk, 0, stream>>>(
        qb16, 512, 0, kvb16, 1024, 0, VtG, x2, norm_g, norm_b, n1f32, n1b16);

    // ---- self attention ----
    mgemm<1, 3><<<dim3(1536 / 128, M / 128), blk, 0, stream>>>(
        n1b16, qkv_wt, qkv_b, nullptr, qkvb16, VtG, M, DIM, 1536, 512, 1024);
    attn_mfma_kernel<<<dim3(1024), blk, 0, stream>>>(
        qkvb16, 1536, 0, qkvb16, 1536, 512, VtG, n1f32, norm_g, norm_b, n1f32, n2b16);

    // ---- MLP ----
    mgemm<1, 1><<<dim3(HIDDEN / 128, M / 128), blk, 0, stream>>>(
        n2b16, fc1_wt, fc1_b, nullptr, hbuf, nullptr, M, DIM, HIDDEN, 0, BIG);
    mgemm<1, 2><<<dim3(512 / 128, M / 128), blk, 0, stream>>>(
        hbuf, fc2_wt, fc2_b, n1f32, out, nullptr, M, HIDDEN, DIM, 0, BIG);
}

// Round 11
// 289.561 us; speedup vs baseline: 1.1007x; 1.0556x over previous
//
#include <hip/hip_runtime.h>
#include <math.h>

#define DIM 512
#define HEADS 16
#define PD 32
#define NSEQ 2048
#define BATCH 4
#define HIDDEN 2048
#define LOG2E 1.44269504088896f

typedef __attribute__((ext_vector_type(8))) __bf16 bf16x8;
typedef __attribute__((ext_vector_type(4))) float f32x4;
typedef __attribute__((ext_vector_type(16))) float f32x16;

__device__ __forceinline__ ushort f2bf(float f) {
    unsigned u = __float_as_uint(f);
    u = (u + 0x7FFFu + ((u >> 16) & 1u)) >> 16;
    return (ushort)u;
}

__device__ __forceinline__ unsigned cvtpk_bf16(float lo, float hi) {
    unsigned r;
    asm("v_cvt_pk_bf16_f32 %0, %1, %2" : "=v"(r) : "v"(lo), "v"(hi));
    return r;
}

__device__ __forceinline__ float exp2_fast(float x) {
    float r;
    asm("v_exp_f32 %0, %1" : "=v"(r) : "v"(x));
    return r;
}

typedef __attribute__((address_space(1))) const unsigned int g_u32;
typedef __attribute__((address_space(3))) unsigned int l_u32;
__device__ __forceinline__ void gload16(const void* g, void* l) {
    __builtin_amdgcn_global_load_lds((g_u32*)g, (l_u32*)l, 16, 0, 0);
}

__device__ __forceinline__ float gelu_exact(float v) {
    return 0.5f * v * (1.0f + erff(v * 0.70710678118654752f));
}

// All 5 weight transposes in one launch: W[K][N] fp32 -> Wt[N][K] bf16.
__global__ __launch_bounds__(256)
void tr_all_kernel(const float* __restrict__ q_w, const float* __restrict__ kv_w,
                   const float* __restrict__ qkv_w, const float* __restrict__ fc1_w,
                   const float* __restrict__ fc2_w, ushort* __restrict__ wtb)
{
    __shared__ float t[32][33];
    const int bid = blockIdx.x;
    const float* W; ushort* Wt; int K, N, lb;
    if (bid < 256)       { W = q_w;   Wt = wtb;           K = 512;  N = 512;  lb = bid; }
    else if (bid < 768)  { W = kv_w;  Wt = wtb + 262144;  K = 512;  N = 1024; lb = bid - 256; }
    else if (bid < 1536) { W = qkv_w; Wt = wtb + 786432;  K = 512;  N = 1536; lb = bid - 768; }
    else if (bid < 2560) { W = fc1_w; Wt = wtb + 1572864; K = 512;  N = 2048; lb = bid - 1536; }
    else                 { W = fc2_w; Wt = wtb + 2621440; K = 2048; N = 512;  lb = bid - 2560; }
    const int nx = N / 32;
    const int n0 = (lb % nx) * 32, k0 = (lb / nx) * 32;
    const int tid = threadIdx.x;
    const int c = tid & 31, r0 = tid >> 5;
    #pragma unroll
    for (int i = 0; i < 4; ++i) {
        int r = r0 + i * 8;
        t[r][c] = W[(size_t)(k0 + r) * N + n0 + c];
    }
    __syncthreads();
    #pragma unroll
    for (int i = 0; i < 4; ++i) {
        int r = r0 + i * 8;
        Wt[(size_t)(n0 + r) * K + k0 + c] = f2bf(t[c][r]);
    }
}

// ---------------- shared GEMM epilogue ----------------
template<int EPI>
__device__ __forceinline__
void gemm_epilogue(f32x4 (&acc)[4][4], const float* __restrict__ bias,
                   const float* __restrict__ resp, void* __restrict__ Cp,
                   ushort* __restrict__ vtp, int Nc, int qcols, int vcol0,
                   int row0, int col0, int wr, int wc, int g, int c)
{
    float bs[4];
    #pragma unroll
    for (int nt = 0; nt < 4; ++nt) bs[nt] = bias[col0 + wc * 64 + nt * 16 + c];

    #pragma unroll
    for (int mt = 0; mt < 4; ++mt) {
        const int rb = row0 + wr * 64 + mt * 16 + g * 4;
        #pragma unroll
        for (int nt = 0; nt < 4; ++nt) {
            const int col = col0 + wc * 64 + nt * 16 + c;
            if (EPI == 3 && col >= vcol0) {
                int cc = col - vcol0;
                int hh = cc >> 5, pd = cc & 31;
                int bq = rb >> 11, ntok = rb & 2047;
                union { ushort u[4]; uint2 v; } pk;
                #pragma unroll
                for (int reg = 0; reg < 4; ++reg)
                    pk.u[reg] = f2bf(acc[mt][nt][reg] + bs[nt]);
                *(uint2*)&vtp[((size_t)(bq * 16 + hh) * 32 + pd) * 2048 + ntok] = pk.v;
            } else {
                #pragma unroll
                for (int reg = 0; reg < 4; ++reg) {
                    int r = rb + reg;
                    float v = acc[mt][nt][reg] + bs[nt];
                    if (EPI == 1) {
                        ((ushort*)Cp)[(size_t)r * Nc + col] = f2bf(gelu_exact(v));
                    } else if (EPI == 2) {
                        ((float*)Cp)[(size_t)r * Nc + col] = v + resp[(size_t)r * Nc + col];
                    } else {
                        float v2 = (col < qcols) ? v * LOG2E : v;
                        ((ushort*)Cp)[(size_t)r * Nc + col] = f2bf(v2);
                    }
                }
            }
        }
    }
}

// bf16 MFMA GEMM, fp32 A (convert in reg-staging), 2-barrier K-loop.
// Used only for the kv / q projections (A = x1/x2 fp32).
template<int EPI>
__global__ __launch_bounds__(256)
void mgemm(const float* __restrict__ Ap, const ushort* __restrict__ Bt,
           const float* __restrict__ bias, const float* __restrict__ resp,
           void* __restrict__ Cp, ushort* __restrict__ vtp,
           int M, int K, int Nc, int qcols, int vcol0)
{
    __shared__ __align__(16) ushort As[128 * 32];
    __shared__ __align__(16) ushort Bs[128 * 32];

    const int tid = threadIdx.x;
    const int wid = tid >> 6, ln = tid & 63;
    const int g = ln >> 4, c = ln & 15;
    const int wr = wid >> 1, wc = wid & 1;

    const int nwg = gridDim.x * gridDim.y;
    const int lid = blockIdx.y * gridDim.x + blockIdx.x;
    const int wg  = (lid & 7) * (nwg >> 3) + (lid >> 3);
    const int by = wg / gridDim.x, bx = wg % gridDim.x;
    const int row0 = by * 128, col0 = bx * 128;

    const f32x4 fzero = {0.f, 0.f, 0.f, 0.f};
    f32x4 acc[4][4];
    #pragma unroll
    for (int i = 0; i < 4; ++i)
        #pragma unroll
        for (int j = 0; j < 4; ++j) acc[i][j] = fzero;

    const int srow = tid >> 1, skh = tid & 1;
    const int w3 = (srow >> 1) & 3;
    const int ws0 = (2 * skh) ^ w3, ws1 = (2 * skh + 1) ^ w3;
    ushort* asw0 = &As[srow * 32 + ws0 * 8];
    ushort* asw1 = &As[srow * 32 + ws1 * 8];
    ushort* bsw0 = &Bs[srow * 32 + ws0 * 8];
    ushort* bsw1 = &Bs[srow * 32 + ws1 * 8];

    const int ps = (c >> 1) & 3;

    for (int k0 = 0; k0 < K; k0 += 32) {
        {
            const float4* ap = (const float4*)(Ap + (size_t)(row0 + srow) * K + k0 + skh * 16);
            float4 f0 = ap[0], f1 = ap[1], f2 = ap[2], f3 = ap[3];
            union { ushort u[16]; uint4 v[2]; } t;
            t.u[0] = f2bf(f0.x);  t.u[1] = f2bf(f0.y);  t.u[2] = f2bf(f0.z);  t.u[3] = f2bf(f0.w);
            t.u[4] = f2bf(f1.x);  t.u[5] = f2bf(f1.y);  t.u[6] = f2bf(f1.z);  t.u[7] = f2bf(f1.w);
            t.u[8] = f2bf(f2.x);  t.u[9] = f2bf(f2.y);  t.u[10] = f2bf(f2.z); t.u[11] = f2bf(f2.w);
            t.u[12] = f2bf(f3.x); t.u[13] = f2bf(f3.y); t.u[14] = f2bf(f3.z); t.u[15] = f2bf(f3.w);
            *(uint4*)asw0 = t.v[0];
            *(uint4*)asw1 = t.v[1];
        }
        {
            const uint4* bp = (const uint4*)(Bt + (size_t)(col0 + srow) * K + k0 + skh * 16);
            *(uint4*)bsw0 = bp[0];
            *(uint4*)bsw1 = bp[1];
        }
        __syncthreads();

        bf16x8 a[4], b[4];
        #pragma unroll
        for (int mt = 0; mt < 4; ++mt)
            a[mt] = *(const bf16x8*)&As[(wr * 64 + mt * 16 + c) * 32 + ((g ^ ps) * 8)];
        #pragma unroll
        for (int nt = 0; nt < 4; ++nt)
            b[nt] = *(const bf16x8*)&Bs[(wc * 64 + nt * 16 + c) * 32 + ((g ^ ps) * 8)];

        #pragma unroll
        for (int mt = 0; mt < 4; ++mt)
            #pragma unroll
            for (int nt = 0; nt < 4; ++nt)
                acc[mt][nt] = __builtin_amdgcn_mfma_f32_16x16x32_bf16(a[mt], b[nt], acc[mt][nt], 0, 0, 0);
        __syncthreads();
    }

    gemm_epilogue<EPI>(acc, bias, resp, Cp, vtp, Nc, qcols, vcol0,
                       row0, col0, wr, wc, g, c);
}

// bf16 MFMA GEMM, bf16 A, global_load_lds double-buffered pipeline:
// prologue STAGE, then per K-step: barrier (drains vmcnt, buf ready) ->
// issue STAGE(next tile, other buf) -> ds_read frags -> 16 MFMA.
// WAR on the read buffer is protected by the NEXT barrier (m97 structure).
// LDS dest linear; per-lane global SOURCE carries the inverse XOR swizzle
// (chunk p: row=p>>2, q4=(p&3)^((row>>1)&3)) so ds_read slot g^ps is
// conflict-free, same algebra as the reg-staged path.
template<int EPI>
__global__ __launch_bounds__(256)
void mgemm_bf(const ushort* __restrict__ Ap, const ushort* __restrict__ Bt,
              const float* __restrict__ bias, const float* __restrict__ resp,
              void* __restrict__ Cp, ushort* __restrict__ vtp,
              int M, int K, int Nc, int qcols, int vcol0)
{
    __shared__ __align__(16) ushort As[2][128 * 32];
    __shared__ __align__(16) ushort Bs[2][128 * 32];

    const int tid = threadIdx.x;
    const int wid = tid >> 6, ln = tid & 63;
    const int g = ln >> 4, c = ln & 15;
    const int wr = wid >> 1, wc = wid & 1;

    const int nwg = gridDim.x * gridDim.y;
    const int lid = blockIdx.y * gridDim.x + blockIdx.x;
    const int wg  = (lid & 7) * (nwg >> 3) + (lid >> 3);
    const int by = wg / gridDim.x, bx = wg % gridDim.x;
    const int row0 = by * 128, col0 = bx * 128;

    const f32x4 fzero = {0.f, 0.f, 0.f, 0.f};
    f32x4 acc[4][4];
    #pragma unroll
    for (int i = 0; i < 4; ++i)
        #pragma unroll
        for (int j = 0; j < 4; ++j) acc[i][j] = fzero;

    // staging: chunk p = i*256 + wid*64 + ln  (i = 0,1); row = p>>2,
    // source k-chunk q4 = (p&3) ^ ((row>>1)&3); LDS dest linear at p*16B.
    const ushort* asrc[2];
    const ushort* bsrc[2];
    int ldst[2];
    #pragma unroll
    for (int i = 0; i < 2; ++i) {
        int p = i * 256 + wid * 64 + ln;
        int row = p >> 2;
        int q4 = (p & 3) ^ ((row >> 1) & 3);
        asrc[i] = Ap + (size_t)(row0 + row) * K + q4 * 8;
        bsrc[i] = Bt + (size_t)(col0 + row) * K + q4 * 8;
        ldst[i] = (i * 256 + wid * 64) * 8;   // wave-uniform, ushorts
    }

#define GSTAGE(bi, kk)                                   \
    {                                                    \
        gload16(asrc[0] + (kk), &As[bi][ldst[0]]);       \
        gload16(asrc[1] + (kk), &As[bi][ldst[1]]);       \
        gload16(bsrc[0] + (kk), &Bs[bi][ldst[0]]);       \
        gload16(bsrc[1] + (kk), &Bs[bi][ldst[1]]);       \
    }

    const int ps = (c >> 1) & 3;
    const int nk = K / 32;

    GSTAGE(0, 0);

    for (int ks = 0; ks < nk; ++ks) {
        __syncthreads();                     // vmcnt drain: buf[ks&1] ready
        if (ks + 1 < nk) GSTAGE((ks + 1) & 1, (ks + 1) * 32);
        const ushort* Ab = As[ks & 1];
        const ushort* Bb = Bs[ks & 1];

        bf16x8 a[4], b[4];
        #pragma unroll
        for (int mt = 0; mt < 4; ++mt)
            a[mt] = *(const bf16x8*)&Ab[(wr * 64 + mt * 16 + c) * 32 + ((g ^ ps) * 8)];
        #pragma unroll
        for (int nt = 0; nt < 4; ++nt)
            b[nt] = *(const bf16x8*)&Bb[(wc * 64 + nt * 16 + c) * 32 + ((g ^ ps) * 8)];

        #pragma unroll
        for (int mt = 0; mt < 4; ++mt)
            #pragma unroll
            for (int nt = 0; nt < 4; ++nt)
                acc[mt][nt] = __builtin_amdgcn_mfma_f32_16x16x32_bf16(a[mt], b[nt], acc[mt][nt], 0, 0, 0);
    }
#undef GSTAGE

    gemm_epilogue<EPI>(acc, bias, resp, Cp, vtp, Nc, qcols, vcol0,
                       row0, col0, wr, wc, g, c);
}

// MFMA flash attention + fused residual + LayerNorm epilogue (round-10,
// verified). Maxless exp2-domain softmax; 4-chain rsum; KVBLK=128 dbuf via
// global_load_lds; V^T precomputed; setprio around MFMA clusters;
// buggy heads-merge perm + residual + in-register LayerNorm epilogue.
__global__ __launch_bounds__(256)
void attn_mfma_kernel(const ushort* __restrict__ qb_, int qstride, int qoff,
                      const ushort* __restrict__ kb_, int kstride, int koff,
                      const ushort* __restrict__ vtg,
                      const float* res, const float* __restrict__ gptr,
                      const float* __restrict__ bptr,
                      float* nf32, ushort* __restrict__ nb16)
{
    __shared__ __align__(16) ushort Klds[2][128 * 32];
    __shared__ __align__(16) ushort Vtlds[2][32 * 128];

    const int tid = threadIdx.x;
    const int w   = tid >> 6;
    const int ln  = tid & 63;
    const int c32 = ln & 31;
    const int hi  = ln >> 5;

    const int bid = blockIdx.x;
    const int xcd = bid & 7, jj = bid >> 3;
    const int bh = xcd + 8 * (jj >> 4);
    const int qt = jj & 15;
    const int b = bh >> 4, h = bh & 15;
    const size_t rowbase = (size_t)b * NSEQ;
    const int qt0 = qt * 128 + w * 32;
    const int n = qt0 + c32;

    bf16x8 qfrag[2];
    #pragma unroll
    for (int ph = 0; ph < 2; ++ph)
        qfrag[ph] = *(const bf16x8*)(qb_ + (rowbase + n) * qstride + qoff
                                     + h * PD + ph * 16 + hi * 8);

    const ushort* ks[2];
    const ushort* vs[2];
    int kd[2], vd[2];
    #pragma unroll
    for (int i = 0; i < 2; ++i) {
        int ch = 2 * w + i;
        int kvc = ch * 16 + (ln >> 2);
        int q4  = (ln & 3) ^ ((kvc >> 1) & 3);
        ks[i] = kb_ + (rowbase + kvc) * kstride + koff + h * PD + q4 * 8;
        kd[i] = ch * 512;
        int pdc = ch * 4 + (ln >> 4);
        int kv0 = ((ln & 15) ^ (pdc & 15)) * 8;
        vs[i] = vtg + ((size_t)bh * PD + pdc) * 2048 + kv0;
        vd[i] = ch * 512;
    }

#define STAGE(bi, trow)                                              \
    {                                                                \
        gload16(ks[0] + (size_t)(trow) * kstride, &Klds[bi][kd[0]]); \
        gload16(ks[1] + (size_t)(trow) * kstride, &Klds[bi][kd[1]]); \
        gload16(vs[0] + (trow), &Vtlds[bi][vd[0]]);                  \
        gload16(vs[1] + (trow), &Vtlds[bi][vd[1]]);                  \
    }

    f32x16 oacc, zero16;
    #pragma unroll
    for (int i = 0; i < 16; ++i) { oacc[i] = 0.f; zero16[i] = 0.f; }
    float l = 0.f;

    STAGE(0, 0);

    for (int t = 0; t < NSEQ / 128; ++t) {
        __syncthreads();
        if (t < NSEQ / 128 - 1) STAGE((t + 1) & 1, (t + 1) * 128);
        const ushort* Kb = Klds[t & 1];
        const ushort* Vb = Vtlds[t & 1];

        #pragma unroll
        for (int hh = 0; hh < 2; ++hh) {
            bf16x8 kf[2][2];
            #pragma unroll
            for (int kt = 0; kt < 2; ++kt)
                #pragma unroll
                for (int ph = 0; ph < 2; ++ph) {
                    int slot = (2 * ph + hi) ^ ((c32 >> 1) & 3);
                    kf[kt][ph] = *(const bf16x8*)&Kb[(hh * 64 + kt * 32 + c32) * 32 + slot * 8];
                }
            bf16x8 vf[4];
            #pragma unroll
            for (int j = 0; j < 4; ++j) {
                int slot = (hh * 8 + 2 * j + hi) ^ (c32 & 15);
                vf[j] = *(const bf16x8*)&Vb[c32 * 128 + slot * 8];
            }

            f32x16 st[2];
            __builtin_amdgcn_s_setprio(1);
            #pragma unroll
            for (int kt = 0; kt < 2; ++kt) {
                st[kt] = __builtin_amdgcn_mfma_f32_32x32x16_bf16(kf[kt][0], qfrag[0], zero16, 0, 0, 0);
                st[kt] = __builtin_amdgcn_mfma_f32_32x32x16_bf16(kf[kt][1], qfrag[1], st[kt], 0, 0, 0);
            }
            __builtin_amdgcn_s_setprio(0);

            float r0 = 0.f, r1 = 0.f, r2 = 0.f, r3 = 0.f;
            #pragma unroll
            for (int kt = 0; kt < 2; ++kt) {
                #pragma unroll
                for (int i = 0; i < 4; ++i) {
                    float p0 = exp2_fast(st[kt][i * 4 + 0]);
                    float p1 = exp2_fast(st[kt][i * 4 + 1]);
                    float p2 = exp2_fast(st[kt][i * 4 + 2]);
                    float p3 = exp2_fast(st[kt][i * 4 + 3]);
                    st[kt][i * 4 + 0] = p0; r0 += p0;
                    st[kt][i * 4 + 1] = p1; r1 += p1;
                    st[kt][i * 4 + 2] = p2; r2 += p2;
                    st[kt][i * 4 + 3] = p3; r3 += p3;
                }
            }
            float rsum = (r0 + r1) + (r2 + r3);
            rsum += __shfl_xor(rsum, 32);
            l += rsum;

            unsigned wpk[2][4][2];
            #pragma unroll
            for (int kt = 0; kt < 2; ++kt)
                #pragma unroll
                for (int rg = 0; rg < 4; ++rg) {
                    wpk[kt][rg][0] = cvtpk_bf16(st[kt][rg * 4 + 0], st[kt][rg * 4 + 1]);
                    wpk[kt][rg][1] = cvtpk_bf16(st[kt][rg * 4 + 2], st[kt][rg * 4 + 3]);
                }

            __builtin_amdgcn_s_setprio(1);
            #pragma unroll
            for (int j = 0; j < 4; ++j) {
                int kt = j >> 1, rg0 = 2 * (j & 1);
                unsigned x0 = wpk[kt][rg0][0], y0 = wpk[kt][rg0 + 1][0];
                unsigned x1 = wpk[kt][rg0][1], y1 = wpk[kt][rg0 + 1][1];
                asm("v_permlane32_swap_b32 %0, %1" : "+v"(x0), "+v"(y0));
                asm("v_permlane32_swap_b32 %0, %1" : "+v"(x1), "+v"(y1));
                union { unsigned u[4]; bf16x8 v; } pf;
                pf.u[0] = x0; pf.u[1] = x1; pf.u[2] = y0; pf.u[3] = y1;
                oacc = __builtin_amdgcn_mfma_f32_32x32x16_bf16(vf[j], pf.v, oacc, 0, 0, 0);
            }
            __builtin_amdgcn_s_setprio(0);
        }
    }
#undef STAGE

    const float inv = 1.0f / l;
    const int row2 = h * 128 + (n >> 4);
    const int colb = (n & 15) * PD;
    const size_t rowoff = (rowbase + row2) * DIM;

    float xv[16];
    float s = 0.f, ss = 0.f;
    #pragma unroll
    for (int ch = 0; ch < 4; ++ch) {
        float4 r4 = *(const float4*)&res[rowoff + colb + ch * 8 + hi * 4];
        #pragma unroll
        for (int q = 0; q < 4; ++q) {
            float rv = (q == 0) ? r4.x : (q == 1) ? r4.y : (q == 2) ? r4.z : r4.w;
            float x = rv + oacc[ch * 4 + q] * inv;
            xv[ch * 4 + q] = x; s += x; ss += x * x;
        }
    }
    s += __shfl_xor(s, 1);  ss += __shfl_xor(ss, 1);
    s += __shfl_xor(s, 2);  ss += __shfl_xor(ss, 2);
    s += __shfl_xor(s, 4);  ss += __shfl_xor(ss, 4);
    s += __shfl_xor(s, 8);  ss += __shfl_xor(ss, 8);
    s += __shfl_xor(s, 32); ss += __shfl_xor(ss, 32);
    float mu = s * (1.0f / DIM);
    float var = ss * (1.0f / DIM) - mu * mu;
    float rr = rsqrtf(var + 1e-5f);

    #pragma unroll
    for (int ch = 0; ch < 4; ++ch) {
        const int off = colb + ch * 8 + hi * 4;
        float4 g4 = *(const float4*)&gptr[off];
        float4 b4 = *(const float4*)&bptr[off];
        float y0 = (xv[ch * 4 + 0] - mu) * rr * g4.x + b4.x;
        float y1 = (xv[ch * 4 + 1] - mu) * rr * g4.y + b4.y;
        float y2 = (xv[ch * 4 + 2] - mu) * rr * g4.z + b4.z;
        float y3 = (xv[ch * 4 + 3] - mu) * rr * g4.w + b4.w;
        float4 yv = {y0, y1, y2, y3};
        *(float4*)&nf32[rowoff + off] = yv;
        uint2 pk = {cvtpk_bf16(y0, y1), cvtpk_bf16(y2, y3)};
        *(uint2*)&nb16[rowoff + off] = pk;
    }
}

extern "C" void kernel_launch(void* const* d_in, const int* in_sizes, int n_in,
                              void* d_out, int out_size, void* d_ws, size_t ws_size,
                              hipStream_t stream)
{
    const float* x1     = (const float*)d_in[0];
    const float* x2     = (const float*)d_in[1];
    const float* qkv_w  = (const float*)d_in[2];
    const float* qkv_b  = (const float*)d_in[3];
    const float* q_w    = (const float*)d_in[4];
    const float* q_b    = (const float*)d_in[5];
    const float* kv_w   = (const float*)d_in[6];
    const float* kv_b   = (const float*)d_in[7];
    const float* norm_g = (const float*)d_in[8];
    const float* norm_b = (const float*)d_in[9];
    const float* fc1_w  = (const float*)d_in[10];
    const float* fc1_b  = (const float*)d_in[11];
    const float* fc2_w  = (const float*)d_in[12];
    const float* fc2_b  = (const float*)d_in[13];
    float* out = (float*)d_out;
    float* ws  = (float*)d_ws;

    const int M = BATCH * NSEQ;  // 8192
    const int BIG = 1 << 30;

    // ws layout (float offsets), all regions disjoint:
    // [0,2M) weights | [2M,10M) proj_u | [10.5M,12.5M) VtG
    // [13M,17M) n1f32 | [17M,19M) n1b16 | [19M,21M) n2b16
    ushort* wtb    = (ushort*)ws;
    ushort* q_wt   = wtb;
    ushort* kv_wt  = wtb + 262144;
    ushort* qkv_wt = wtb + 786432;
    ushort* fc1_wt = wtb + 1572864;
    ushort* fc2_wt = wtb + 2621440;
    ushort* proj_u = (ushort*)(ws + (size_t)2 * 1024 * 1024);
    ushort* kvb16  = proj_u;                            // 8192x1024
    ushort* qb16   = proj_u + (size_t)8192 * 1024;      // 8192x512
    ushort* qkvb16 = proj_u;                            // 8192x1536
    ushort* hbuf   = proj_u;                            // 8192x2048
    ushort* VtG    = (ushort*)(ws + (size_t)21 * 512 * 1024);  // 10.5M floats
    float*  n1f32  = ws + (size_t)13 * 1024 * 1024;
    ushort* n1b16  = (ushort*)(ws + (size_t)17 * 1024 * 1024);
    ushort* n2b16  = (ushort*)(ws + (size_t)19 * 1024 * 1024);

    dim3 blk(256);

    tr_all_kernel<<<dim3(3584), blk, 0, stream>>>(q_w, kv_w, qkv_w, fc1_w, fc2_w, wtb);

    // ---- cross attention ----
    mgemm<3><<<dim3(1024 / 128, M / 128), blk, 0, stream>>>(
        x1, kv_wt, kv_b, nullptr, kvb16, VtG, M, DIM, 1024, 0, 512);
    mgemm<3><<<dim3(512 / 128, M / 128), blk, 0, stream>>>(
        x2, q_wt, q_b, nullptr, qb16, nullptr, M, DIM, 512, 512, BIG);
    attn_mfma_kernel<<<dim3(1024), blk, 0, stream>>>(
        qb16, 512, 0, kvb16, 1024, 0, VtG, x2, norm_g, norm_b, n1f32, n1b16);

    // ---- self attention ----
    mgemm_bf<3><<<dim3(1536 / 128, M / 128), blk, 0, stream>>>(
        n1b16, qkv_wt, qkv_b, nullptr, qkvb16, VtG, M, DIM, 1536, 512, 1024);
    attn_mfma_kernel<<<dim3(1024), blk, 0, stream>>>(
        qkvb16, 1536, 0, qkvb16, 1536, 512, VtG, n1f32, norm_g, norm_b, n1f32, n2b16);

    // ---- MLP ----
    mgemm_bf<1><<<dim3(HIDDEN / 128, M / 128), blk, 0, stream>>>(
        n2b16, fc1_wt, fc1_b, nullptr, hbuf, nullptr, M, DIM, HIDDEN, 0, BIG);
    mgemm_bf<2><<<dim3(512 / 128, M / 128), blk, 0, stream>>>(
        hbuf, fc2_wt, fc2_b, n1f32, out, nullptr, M, HIDDEN, DIM, 0, BIG);
}